// Round 8
// baseline (433.398 us; speedup 1.0000x reference)
//
#include <hip/hip_runtime.h>
#include <hip/hip_fp16.h>

// HashGrid encode: N=524288, L=16, F=2, T=2^19.
// R12 (session R8): fused main with ZERO block turnover.
//  Wall (R0/R1/R3/R7): divergent-gather service ~0.2-0.25 lines/cy/CU,
//  invariant to occupancy, MLP, residency. Time ~ req/pt x 3.2-4.3us.
//  Best rate = R0's fused kernel (3.2): 1024 blocks ~= residency => no
//  block turnover => natural level lockstep, compulsory FETCH.
//  R5's fused thrash was TURNOVER (2048 blocks, ~7 resident): late blocks
//  at level 0 while early at level 9 => 2 table-sets live => L2 thrash.
//  Design: grid 1024 = 4 blocks/CU exactly co-resident (launch_bounds
//  (256,4), VGPR<=128), 2 pts/thread, levels straight-line with immediate
//  pair stores (spill-proof, R5-validated). Hash pairs (sync-sensitive,
//  4MB epochs) first; dense 0-3 (4MB) next; dense 4-5 (streams) last.
//  Requests/pt ~62 (oct dense 1 line/level, aligned-4 hash groups 5/level)
//  vs R0's 72.

#define HG_L     16
#define HG_LOG_T 19
#define HG_T     (1u << HG_LOG_T)
#define HG_N     524288u
#define HP1      2654435761u
#define HP2      805459861u

// dense levels 0..5: resolution {16,22,30,42,58,80} -> S = res+1
#define DS0 17u
#define DS1 23u
#define DS2 31u
#define DS3 43u
#define DS4 59u
#define DS5 81u
#define DOFF0 0u
#define DOFF1 4913u      // +17^3
#define DOFF2 17080u     // +23^3
#define DOFF3 46871u     // +31^3
#define DOFF4 126378u    // +43^3
#define DOFF5 331757u    // +59^3
#define DTOTAL 863198u   // +81^3  cells; 32 B each (oct) = 27.6 MB

// ws layout: [0, 10*T*4) hashed pair tables (levels 6..15, rebased l-6),
//            then oct entries (2 x uint4 per dense cell).
#define TAB_BYTES ((size_t)10u * HG_T * 4u)    // 20.97 MB

#define NB_INTER 5120u                          // (10*T/4)/256
#define NB_OCT   6744u                          // ceil(2*DTOTAL/256)

__device__ __forceinline__ unsigned pack_h2(float f0, float f1) {
    __half2 h = __floats2half2_rn(f0, f1);
    return *reinterpret_cast<unsigned*>(&h);
}

// Fused prep: blocks [0, NB_INTER) interleave hashed levels 6..15 into the
// half2 pair table; blocks [NB_INTER, ..) build dense OCT half-entries
// (one thread = one 16B half: z-slab zh of cell's quad).
__global__ __launch_bounds__(256) void hg_prep(
    const float* __restrict__ hm,   // [L, F, T]
    __half2* __restrict__ wst,      // [10, T] rebased hashed tables
    uint4* __restrict__ oct)        // [DTOTAL*2]
{
    const unsigned bid = blockIdx.x;
    const unsigned M = HG_T - 1u;
    if (bid < NB_INTER) {
        const unsigned u  = (bid * 256u + threadIdx.x) * 4u;  // 0..10*T
        const unsigned l6 = u >> HG_LOG_T;                    // 0..9
        const unsigned t  = u & M;
        const float* base = hm + (size_t)(l6 + 6u) * (2u * HG_T);
        const float4 a = *reinterpret_cast<const float4*>(base + t);          // f=0
        const float4 b = *reinterpret_cast<const float4*>(base + HG_T + t);   // f=1
        uint4 o;
        o.x = pack_h2(a.x, b.x);
        o.y = pack_h2(a.y, b.y);
        o.z = pack_h2(a.z, b.z);
        o.w = pack_h2(a.w, b.w);
        *reinterpret_cast<uint4*>(wst + u) = o;
        return;
    }
    const unsigned j = (bid - NB_INTER) * 256u + threadIdx.x; // 0..2*DTOTAL
    if (j >= 2u * DTOTAL) return;
    const unsigned cell = j >> 1;
    const unsigned zh   = j & 1u;
    unsigned l, S, off;
    if      (cell < DOFF1) { l = 0; S = DS0; off = DOFF0; }
    else if (cell < DOFF2) { l = 1; S = DS1; off = DOFF1; }
    else if (cell < DOFF3) { l = 2; S = DS2; off = DOFF2; }
    else if (cell < DOFF4) { l = 3; S = DS3; off = DOFF3; }
    else if (cell < DOFF5) { l = 4; S = DS4; off = DOFF4; }
    else                   { l = 5; S = DS5; off = DOFF5; }
    const unsigned i  = cell - off;
    const unsigned x  = i % S;
    const unsigned t1 = i / S;
    const unsigned y  = t1 % S;
    const unsigned z  = t1 / S + zh;
    const unsigned hz = z * HP2;
    const unsigned hy0 = y * HP1, hy1 = hy0 + HP1;
    const unsigned i00 = (hy0 ^ hz ^ x) & M;
    const unsigned i10 = (hy0 ^ hz ^ (x + 1u)) & M;
    const unsigned i01 = (hy1 ^ hz ^ x) & M;
    const unsigned i11 = (hy1 ^ hz ^ (x + 1u)) & M;
    const float* b0 = hm + (size_t)l * (2u * HG_T);
    uint4 o;
    o.x = pack_h2(b0[i00], b0[i00 + HG_T]);
    o.y = pack_h2(b0[i10], b0[i10 + HG_T]);
    o.z = pack_h2(b0[i01], b0[i01 + HG_T]);
    o.w = pack_h2(b0[i11], b0[i11 + HG_T]);
    oct[j] = o;
}

__device__ __forceinline__ float2 hfv(unsigned raw) {
    return __half22float2(*reinterpret_cast<const __half2*>(&raw));
}

// select entry k (0..3) of an aligned 4-entry group (VALU cndmask chain)
__device__ __forceinline__ unsigned sel4(const uint4& g, unsigned k) {
    const unsigned lo = (k & 1u) ? g.y : g.x;
    const unsigned hi = (k & 1u) ? g.w : g.z;
    return (k & 2u) ? hi : lo;
}

template <unsigned S, unsigned OFF>
__device__ __forceinline__ float2 enc_dense(
    float px, float py, float pz, float res,
    const uint4* __restrict__ oct)
{
    const float xs0 = px * res, xs1 = py * res, xs2 = pz * res;
    const float fl0 = floorf(xs0), fl1 = floorf(xs1), fl2 = floorf(xs2);
    const float fr0 = xs0 - fl0, fr1 = xs1 - fl1, fr2 = xs2 - fl2;
    const unsigned x0 = (unsigned)fl0;
    const unsigned y0 = (unsigned)fl1;
    const unsigned z0 = (unsigned)fl2;

    const unsigned i = ((z0 * S + y0) * S + x0 + OFF) * 2u;
    const uint4 q0 = oct[i];        // z0 slab quad: v00,v10,v01,v11
    const uint4 q1 = oct[i + 1u];   // z0+1 slab quad (same 64B line)

    const float w0x = 1.0f - fr0, w1x = fr0;
    const float w0y = 1.0f - fr1, w1y = fr1;
    const float w0z = 1.0f - fr2, w1z = fr2;

    const float2 a00 = hfv(q0.x), a10 = hfv(q0.y), a01 = hfv(q0.z), a11 = hfv(q0.w);
    const float2 b00 = hfv(q1.x), b10 = hfv(q1.y), b01 = hfv(q1.z), b11 = hfv(q1.w);

    const float s0x = w0y * (w0x * a00.x + w1x * a10.x) + w1y * (w0x * a01.x + w1x * a11.x);
    const float s0y = w0y * (w0x * a00.y + w1x * a10.y) + w1y * (w0x * a01.y + w1x * a11.y);
    const float s1x = w0y * (w0x * b00.x + w1x * b10.x) + w1y * (w0x * b01.x + w1x * b11.x);
    const float s1y = w0y * (w0x * b00.y + w1x * b10.y) + w1y * (w0x * b01.y + w1x * b11.y);

    return make_float2(w0z * s0x + w1z * s1x, w0z * s0y + w1z * s1y);
}

__device__ __forceinline__ float2 enc_hash(
    float px, float py, float pz, float res,
    const uint2* __restrict__ tab2)   // level's table as aligned pairs
{
    const float xs0 = px * res, xs1 = py * res, xs2 = pz * res;
    const float fl0 = floorf(xs0), fl1 = floorf(xs1), fl2 = floorf(xs2);
    const float fr0 = xs0 - fl0, fr1 = xs1 - fl1, fr2 = xs2 - fl2;
    const unsigned x0 = (unsigned)fl0;
    const unsigned y0 = (unsigned)fl1;
    const unsigned z0 = (unsigned)fl2;
    const unsigned M = HG_T - 1u;
    const uint4* tab4 = reinterpret_cast<const uint4*>(tab2);

    const unsigned hy0 = y0 * HP1, hy1 = hy0 + HP1;
    const unsigned hz0 = z0 * HP2, hz1 = hz0 + HP2;
    const unsigned H0 = hy0 ^ hz0;
    const unsigned H1 = hy1 ^ hz0;
    const unsigned H2 = hy0 ^ hz1;
    const unsigned H3 = hy1 ^ hz1;
    const unsigned x1 = x0 + 1u;

    const unsigned i00 = (H0 ^ x0) & M, i01 = (H0 ^ x1) & M;
    const unsigned i10 = (H1 ^ x0) & M, i11 = (H1 ^ x1) & M;
    const unsigned i20 = (H2 ^ x0) & M, i21 = (H2 ^ x1) & M;
    const unsigned i30 = (H3 ^ x0) & M, i31 = (H3 ^ x1) & M;

    // one 16B group load per corner-row covers BOTH x corners when
    // (x0&3)!=3 (i0 and i1 share the aligned-4 group).
    const uint4 g0 = tab4[i00 >> 2];
    const uint4 g1 = tab4[i10 >> 2];
    const uint4 g2 = tab4[i20 >> 2];
    const uint4 g3 = tab4[i30 >> 2];

    unsigned c00 = sel4(g0, i00 & 3u), c01 = sel4(g0, i01 & 3u);
    unsigned c10 = sel4(g1, i10 & 3u), c11 = sel4(g1, i11 & 3u);
    unsigned c20 = sel4(g2, i20 & 3u), c21 = sel4(g2, i21 & 3u);
    unsigned c30 = sel4(g3, i30 & 3u), c31 = sel4(g3, i31 & 3u);

    if ((x0 & 3u) == 3u) {   // x1 crossed the group (25% of lanes): reload
        { const uint2 p = tab2[i01 >> 1]; c01 = (i01 & 1u) ? p.y : p.x; }
        { const uint2 p = tab2[i11 >> 1]; c11 = (i11 & 1u) ? p.y : p.x; }
        { const uint2 p = tab2[i21 >> 1]; c21 = (i21 & 1u) ? p.y : p.x; }
        { const uint2 p = tab2[i31 >> 1]; c31 = (i31 & 1u) ? p.y : p.x; }
    }

    const float w0x = 1.0f - fr0, w1x = fr0;
    const float w00 = (1.0f - fr1) * (1.0f - fr2);
    const float w10 = fr1 * (1.0f - fr2);
    const float w01 = (1.0f - fr1) * fr2;
    const float w11 = fr1 * fr2;

    float ax = 0.0f, ay = 0.0f;
    { const float2 v0 = hfv(c00), v1 = hfv(c01);
      ax += w00 * (w0x * v0.x + w1x * v1.x);
      ay += w00 * (w0x * v0.y + w1x * v1.y); }
    { const float2 v0 = hfv(c10), v1 = hfv(c11);
      ax += w10 * (w0x * v0.x + w1x * v1.x);
      ay += w10 * (w0x * v0.y + w1x * v1.y); }
    { const float2 v0 = hfv(c20), v1 = hfv(c21);
      ax += w01 * (w0x * v0.x + w1x * v1.x);
      ay += w01 * (w0x * v0.y + w1x * v1.y); }
    { const float2 v0 = hfv(c30), v1 = hfv(c31);
      ax += w11 * (w0x * v0.x + w1x * v1.x);
      ay += w11 * (w0x * v0.y + w1x * v1.y); }
    return make_float2(ax, ay);
}

// Fused main: 1024 blocks x 256 thr x 2 pts. All blocks co-resident
// (4 blocks/CU via launch_bounds(256,4)): zero turnover -> natural level
// lockstep -> each 4MB level-pair epoch stays L2-resident.
__global__ __launch_bounds__(256, 4) void hg_main(
    const float* __restrict__ x,          // [N, 3]
    const uint2* __restrict__ tab2,       // hashed pair tables [10*T/2]
    const uint4* __restrict__ oct,        // dense oct lattices [DTOTAL*2]
    const float* __restrict__ resolution, // [L]
    float*       __restrict__ out)        // [N, 32]
{
    const unsigned tid = threadIdx.x;
    const unsigned p0  = blockIdx.x * 512u + tid;
    const unsigned p1  = p0 + 256u;
    const float ax0 = x[p0 * 3 + 0], ay0 = x[p0 * 3 + 1], az0 = x[p0 * 3 + 2];
    const float ax1 = x[p1 * 3 + 0], ay1 = x[p1 * 3 + 1], az1 = x[p1 * 3 + 2];
    float4* d0 = reinterpret_cast<float4*>(out + (size_t)p0 * 32u);
    float4* d1 = reinterpret_cast<float4*>(out + (size_t)p1 * 32u);

    // ---- hashed level pairs first (sync-sensitive 4MB epochs) ----
#define HPAIR(L0)                                                              \
    {                                                                          \
        const uint2* t0 = tab2 + (size_t)((L0) - 6) * (HG_T / 2u);             \
        const uint2* t1 = tab2 + (size_t)((L0) - 5) * (HG_T / 2u);             \
        const float r0 = resolution[(L0)], r1 = resolution[(L0) + 1];          \
        const float2 a0 = enc_hash(ax0, ay0, az0, r0, t0);                     \
        const float2 b0 = enc_hash(ax0, ay0, az0, r1, t1);                     \
        const float2 a1 = enc_hash(ax1, ay1, az1, r0, t0);                     \
        const float2 b1 = enc_hash(ax1, ay1, az1, r1, t1);                     \
        d0[3 + ((L0) - 6) / 2] = make_float4(a0.x, a0.y, b0.x, b0.y);          \
        d1[3 + ((L0) - 6) / 2] = make_float4(a1.x, a1.y, b1.x, b1.y);          \
    }
    HPAIR(6)
    HPAIR(8)
    HPAIR(10)
    HPAIR(12)
    HPAIR(14)
#undef HPAIR

    // ---- dense levels 0..3 (4MB oct region, resident) ----
    {
        const float r0 = resolution[0], r1 = resolution[1];
        const float2 a0 = enc_dense<DS0, DOFF0>(ax0, ay0, az0, r0, oct);
        const float2 b0 = enc_dense<DS1, DOFF1>(ax0, ay0, az0, r1, oct);
        const float2 a1 = enc_dense<DS0, DOFF0>(ax1, ay1, az1, r0, oct);
        const float2 b1 = enc_dense<DS1, DOFF1>(ax1, ay1, az1, r1, oct);
        d0[0] = make_float4(a0.x, a0.y, b0.x, b0.y);
        d1[0] = make_float4(a1.x, a1.y, b1.x, b1.y);
    }
    {
        const float r2 = resolution[2], r3 = resolution[3];
        const float2 a0 = enc_dense<DS2, DOFF2>(ax0, ay0, az0, r2, oct);
        const float2 b0 = enc_dense<DS3, DOFF3>(ax0, ay0, az0, r3, oct);
        const float2 a1 = enc_dense<DS2, DOFF2>(ax1, ay1, az1, r2, oct);
        const float2 b1 = enc_dense<DS3, DOFF3>(ax1, ay1, az1, r3, oct);
        d0[1] = make_float4(a0.x, a0.y, b0.x, b0.y);
        d1[1] = make_float4(a1.x, a1.y, b1.x, b1.y);
    }
    // ---- dense levels 4..5 last (23.5MB, streams; drift-tolerant) ----
    {
        const float r4 = resolution[4], r5 = resolution[5];
        const float2 a0 = enc_dense<DS4, DOFF4>(ax0, ay0, az0, r4, oct);
        const float2 b0 = enc_dense<DS5, DOFF5>(ax0, ay0, az0, r5, oct);
        const float2 a1 = enc_dense<DS4, DOFF4>(ax1, ay1, az1, r4, oct);
        const float2 b1 = enc_dense<DS5, DOFF5>(ax1, ay1, az1, r5, oct);
        d0[2] = make_float4(a0.x, a0.y, b0.x, b0.y);
        d1[2] = make_float4(a1.x, a1.y, b1.x, b1.y);
    }
}

extern "C" void kernel_launch(void* const* d_in, const int* in_sizes, int n_in,
                              void* d_out, int out_size, void* d_ws, size_t ws_size,
                              hipStream_t stream) {
    const float* x          = (const float*)d_in[0];
    const float* hashmap    = (const float*)d_in[1];
    const float* resolution = (const float*)d_in[2];
    float* out              = (float*)d_out;

    __half2* wst = (__half2*)d_ws;                         // 20.97 MB hashed tables
    uint4*   oct = (uint4*)((char*)d_ws + TAB_BYTES);      // 27.6 MB oct lattices
    const uint2* tab2 = (const uint2*)d_ws;

    hipLaunchKernelGGL(hg_prep, dim3(NB_INTER + NB_OCT), dim3(256), 0, stream,
                       hashmap, wst, oct);

    hipLaunchKernelGGL(hg_main, dim3(HG_N / 512u), dim3(256), 0, stream,
                       x, tab2, oct, resolution, out);
}

// Round 9
// 419.247 us; speedup vs baseline: 1.0338x; 1.0338x over previous
//
#include <hip/hip_runtime.h>
#include <hip/hip_fp16.h>

// HashGrid encode: N=524288, L=16, F=2, T=2^19.
// R13 (session R9): R8 + BARRIER LOCKSTEP.
//  Model (R0/R3/R7 clean runs): line-request wall ~0.25 lines/cy/CU
//  (~9.8 TB/s of 64B lines), invariant to occupancy/MLP/residency.
//  time = max(lines*64B/9.8TB/s, HBM_bytes/3.5TB/s). 56 lines/pt =>
//  line-term ~192us.
//  R8 post-mortem: co-residency (1024 blocks) did NOT give lockstep --
//  FETCH 930MB (drifted waves, many table epochs live, L2 thrash) =>
//  HBM term 265us bound the kernel at 316us.
//  Fix (single variable vs R8): __syncthreads() after each level-pair
//  epoch. Waves of a block re-align at every pair; identical code across
//  co-resident blocks keeps inter-block drift ~launch-skew. Live set back
//  to <=2 tables => HBM term under the line wall.

#define HG_L     16
#define HG_LOG_T 19
#define HG_T     (1u << HG_LOG_T)
#define HG_N     524288u
#define HP1      2654435761u
#define HP2      805459861u

// dense levels 0..5: resolution {16,22,30,42,58,80} -> S = res+1
#define DS0 17u
#define DS1 23u
#define DS2 31u
#define DS3 43u
#define DS4 59u
#define DS5 81u
#define DOFF0 0u
#define DOFF1 4913u      // +17^3
#define DOFF2 17080u     // +23^3
#define DOFF3 46871u     // +31^3
#define DOFF4 126378u    // +43^3
#define DOFF5 331757u    // +59^3
#define DTOTAL 863198u   // +81^3  cells; 32 B each (oct) = 27.6 MB

// ws layout: [0, 10*T*4) hashed pair tables (levels 6..15, rebased l-6),
//            then oct entries (2 x uint4 per dense cell).
#define TAB_BYTES ((size_t)10u * HG_T * 4u)    // 20.97 MB

#define NB_INTER 5120u                          // (10*T/4)/256
#define NB_OCT   6744u                          // ceil(2*DTOTAL/256)

__device__ __forceinline__ unsigned pack_h2(float f0, float f1) {
    __half2 h = __floats2half2_rn(f0, f1);
    return *reinterpret_cast<unsigned*>(&h);
}

// Fused prep: blocks [0, NB_INTER) interleave hashed levels 6..15 into the
// half2 pair table; blocks [NB_INTER, ..) build dense OCT half-entries
// (one thread = one 16B half: z-slab zh of cell's quad).
__global__ __launch_bounds__(256) void hg_prep(
    const float* __restrict__ hm,   // [L, F, T]
    __half2* __restrict__ wst,      // [10, T] rebased hashed tables
    uint4* __restrict__ oct)        // [DTOTAL*2]
{
    const unsigned bid = blockIdx.x;
    const unsigned M = HG_T - 1u;
    if (bid < NB_INTER) {
        const unsigned u  = (bid * 256u + threadIdx.x) * 4u;  // 0..10*T
        const unsigned l6 = u >> HG_LOG_T;                    // 0..9
        const unsigned t  = u & M;
        const float* base = hm + (size_t)(l6 + 6u) * (2u * HG_T);
        const float4 a = *reinterpret_cast<const float4*>(base + t);          // f=0
        const float4 b = *reinterpret_cast<const float4*>(base + HG_T + t);   // f=1
        uint4 o;
        o.x = pack_h2(a.x, b.x);
        o.y = pack_h2(a.y, b.y);
        o.z = pack_h2(a.z, b.z);
        o.w = pack_h2(a.w, b.w);
        *reinterpret_cast<uint4*>(wst + u) = o;
        return;
    }
    const unsigned j = (bid - NB_INTER) * 256u + threadIdx.x; // 0..2*DTOTAL
    if (j >= 2u * DTOTAL) return;
    const unsigned cell = j >> 1;
    const unsigned zh   = j & 1u;
    unsigned l, S, off;
    if      (cell < DOFF1) { l = 0; S = DS0; off = DOFF0; }
    else if (cell < DOFF2) { l = 1; S = DS1; off = DOFF1; }
    else if (cell < DOFF3) { l = 2; S = DS2; off = DOFF2; }
    else if (cell < DOFF4) { l = 3; S = DS3; off = DOFF3; }
    else if (cell < DOFF5) { l = 4; S = DS4; off = DOFF4; }
    else                   { l = 5; S = DS5; off = DOFF5; }
    const unsigned i  = cell - off;
    const unsigned x  = i % S;
    const unsigned t1 = i / S;
    const unsigned y  = t1 % S;
    const unsigned z  = t1 / S + zh;
    const unsigned hz = z * HP2;
    const unsigned hy0 = y * HP1, hy1 = hy0 + HP1;
    const unsigned i00 = (hy0 ^ hz ^ x) & M;
    const unsigned i10 = (hy0 ^ hz ^ (x + 1u)) & M;
    const unsigned i01 = (hy1 ^ hz ^ x) & M;
    const unsigned i11 = (hy1 ^ hz ^ (x + 1u)) & M;
    const float* b0 = hm + (size_t)l * (2u * HG_T);
    uint4 o;
    o.x = pack_h2(b0[i00], b0[i00 + HG_T]);
    o.y = pack_h2(b0[i10], b0[i10 + HG_T]);
    o.z = pack_h2(b0[i01], b0[i01 + HG_T]);
    o.w = pack_h2(b0[i11], b0[i11 + HG_T]);
    oct[j] = o;
}

__device__ __forceinline__ float2 hfv(unsigned raw) {
    return __half22float2(*reinterpret_cast<const __half2*>(&raw));
}

// select entry k (0..3) of an aligned 4-entry group (VALU cndmask chain)
__device__ __forceinline__ unsigned sel4(const uint4& g, unsigned k) {
    const unsigned lo = (k & 1u) ? g.y : g.x;
    const unsigned hi = (k & 1u) ? g.w : g.z;
    return (k & 2u) ? hi : lo;
}

template <unsigned S, unsigned OFF>
__device__ __forceinline__ float2 enc_dense(
    float px, float py, float pz, float res,
    const uint4* __restrict__ oct)
{
    const float xs0 = px * res, xs1 = py * res, xs2 = pz * res;
    const float fl0 = floorf(xs0), fl1 = floorf(xs1), fl2 = floorf(xs2);
    const float fr0 = xs0 - fl0, fr1 = xs1 - fl1, fr2 = xs2 - fl2;
    const unsigned x0 = (unsigned)fl0;
    const unsigned y0 = (unsigned)fl1;
    const unsigned z0 = (unsigned)fl2;

    const unsigned i = ((z0 * S + y0) * S + x0 + OFF) * 2u;
    const uint4 q0 = oct[i];        // z0 slab quad: v00,v10,v01,v11
    const uint4 q1 = oct[i + 1u];   // z0+1 slab quad (same 64B line)

    const float w0x = 1.0f - fr0, w1x = fr0;
    const float w0y = 1.0f - fr1, w1y = fr1;
    const float w0z = 1.0f - fr2, w1z = fr2;

    const float2 a00 = hfv(q0.x), a10 = hfv(q0.y), a01 = hfv(q0.z), a11 = hfv(q0.w);
    const float2 b00 = hfv(q1.x), b10 = hfv(q1.y), b01 = hfv(q1.z), b11 = hfv(q1.w);

    const float s0x = w0y * (w0x * a00.x + w1x * a10.x) + w1y * (w0x * a01.x + w1x * a11.x);
    const float s0y = w0y * (w0x * a00.y + w1x * a10.y) + w1y * (w0x * a01.y + w1x * a11.y);
    const float s1x = w0y * (w0x * b00.x + w1x * b10.x) + w1y * (w0x * b01.x + w1x * b11.x);
    const float s1y = w0y * (w0x * b00.y + w1x * b10.y) + w1y * (w0x * b01.y + w1x * b11.y);

    return make_float2(w0z * s0x + w1z * s1x, w0z * s0y + w1z * s1y);
}

__device__ __forceinline__ float2 enc_hash(
    float px, float py, float pz, float res,
    const uint2* __restrict__ tab2)   // level's table as aligned pairs
{
    const float xs0 = px * res, xs1 = py * res, xs2 = pz * res;
    const float fl0 = floorf(xs0), fl1 = floorf(xs1), fl2 = floorf(xs2);
    const float fr0 = xs0 - fl0, fr1 = xs1 - fl1, fr2 = xs2 - fl2;
    const unsigned x0 = (unsigned)fl0;
    const unsigned y0 = (unsigned)fl1;
    const unsigned z0 = (unsigned)fl2;
    const unsigned M = HG_T - 1u;
    const uint4* tab4 = reinterpret_cast<const uint4*>(tab2);

    const unsigned hy0 = y0 * HP1, hy1 = hy0 + HP1;
    const unsigned hz0 = z0 * HP2, hz1 = hz0 + HP2;
    const unsigned H0 = hy0 ^ hz0;
    const unsigned H1 = hy1 ^ hz0;
    const unsigned H2 = hy0 ^ hz1;
    const unsigned H3 = hy1 ^ hz1;
    const unsigned x1 = x0 + 1u;

    const unsigned i00 = (H0 ^ x0) & M, i01 = (H0 ^ x1) & M;
    const unsigned i10 = (H1 ^ x0) & M, i11 = (H1 ^ x1) & M;
    const unsigned i20 = (H2 ^ x0) & M, i21 = (H2 ^ x1) & M;
    const unsigned i30 = (H3 ^ x0) & M, i31 = (H3 ^ x1) & M;

    // one 16B group load per corner-row covers BOTH x corners when
    // (x0&3)!=3 (i0 and i1 share the aligned-4 group).
    const uint4 g0 = tab4[i00 >> 2];
    const uint4 g1 = tab4[i10 >> 2];
    const uint4 g2 = tab4[i20 >> 2];
    const uint4 g3 = tab4[i30 >> 2];

    unsigned c00 = sel4(g0, i00 & 3u), c01 = sel4(g0, i01 & 3u);
    unsigned c10 = sel4(g1, i10 & 3u), c11 = sel4(g1, i11 & 3u);
    unsigned c20 = sel4(g2, i20 & 3u), c21 = sel4(g2, i21 & 3u);
    unsigned c30 = sel4(g3, i30 & 3u), c31 = sel4(g3, i31 & 3u);

    if ((x0 & 3u) == 3u) {   // x1 crossed the group (25% of lanes): reload
        { const uint2 p = tab2[i01 >> 1]; c01 = (i01 & 1u) ? p.y : p.x; }
        { const uint2 p = tab2[i11 >> 1]; c11 = (i11 & 1u) ? p.y : p.x; }
        { const uint2 p = tab2[i21 >> 1]; c21 = (i21 & 1u) ? p.y : p.x; }
        { const uint2 p = tab2[i31 >> 1]; c31 = (i31 & 1u) ? p.y : p.x; }
    }

    const float w0x = 1.0f - fr0, w1x = fr0;
    const float w00 = (1.0f - fr1) * (1.0f - fr2);
    const float w10 = fr1 * (1.0f - fr2);
    const float w01 = (1.0f - fr1) * fr2;
    const float w11 = fr1 * fr2;

    float ax = 0.0f, ay = 0.0f;
    { const float2 v0 = hfv(c00), v1 = hfv(c01);
      ax += w00 * (w0x * v0.x + w1x * v1.x);
      ay += w00 * (w0x * v0.y + w1x * v1.y); }
    { const float2 v0 = hfv(c10), v1 = hfv(c11);
      ax += w10 * (w0x * v0.x + w1x * v1.x);
      ay += w10 * (w0x * v0.y + w1x * v1.y); }
    { const float2 v0 = hfv(c20), v1 = hfv(c21);
      ax += w01 * (w0x * v0.x + w1x * v1.x);
      ay += w01 * (w0x * v0.y + w1x * v1.y); }
    { const float2 v0 = hfv(c30), v1 = hfv(c31);
      ax += w11 * (w0x * v0.x + w1x * v1.x);
      ay += w11 * (w0x * v0.y + w1x * v1.y); }
    return make_float2(ax, ay);
}

// Fused main: 1024 blocks x 256 thr x 2 pts, all co-resident (4 blocks/CU).
// __syncthreads() after every level-pair epoch enforces wave lockstep so
// only ~1-2 table epochs are live at any instant (L2-resident).
__global__ __launch_bounds__(256, 4) void hg_main(
    const float* __restrict__ x,          // [N, 3]
    const uint2* __restrict__ tab2,       // hashed pair tables [10*T/2]
    const uint4* __restrict__ oct,        // dense oct lattices [DTOTAL*2]
    const float* __restrict__ resolution, // [L]
    float*       __restrict__ out)        // [N, 32]
{
    const unsigned tid = threadIdx.x;
    const unsigned p0  = blockIdx.x * 512u + tid;
    const unsigned p1  = p0 + 256u;
    const float ax0 = x[p0 * 3 + 0], ay0 = x[p0 * 3 + 1], az0 = x[p0 * 3 + 2];
    const float ax1 = x[p1 * 3 + 0], ay1 = x[p1 * 3 + 1], az1 = x[p1 * 3 + 2];
    float4* d0 = reinterpret_cast<float4*>(out + (size_t)p0 * 32u);
    float4* d1 = reinterpret_cast<float4*>(out + (size_t)p1 * 32u);

    // ---- hashed level pairs first (sync-sensitive 4MB epochs) ----
#define HPAIR(L0)                                                              \
    {                                                                          \
        const uint2* t0 = tab2 + (size_t)((L0) - 6) * (HG_T / 2u);             \
        const uint2* t1 = tab2 + (size_t)((L0) - 5) * (HG_T / 2u);             \
        const float r0 = resolution[(L0)], r1 = resolution[(L0) + 1];          \
        const float2 a0 = enc_hash(ax0, ay0, az0, r0, t0);                     \
        const float2 b0 = enc_hash(ax0, ay0, az0, r1, t1);                     \
        const float2 a1 = enc_hash(ax1, ay1, az1, r0, t0);                     \
        const float2 b1 = enc_hash(ax1, ay1, az1, r1, t1);                     \
        d0[3 + ((L0) - 6) / 2] = make_float4(a0.x, a0.y, b0.x, b0.y);          \
        d1[3 + ((L0) - 6) / 2] = make_float4(a1.x, a1.y, b1.x, b1.y);          \
        __syncthreads();                                                       \
    }
    HPAIR(6)
    HPAIR(8)
    HPAIR(10)
    HPAIR(12)
    HPAIR(14)
#undef HPAIR

    // ---- dense levels 0..3 (4MB oct region, resident) ----
    {
        const float r0 = resolution[0], r1 = resolution[1];
        const float2 a0 = enc_dense<DS0, DOFF0>(ax0, ay0, az0, r0, oct);
        const float2 b0 = enc_dense<DS1, DOFF1>(ax0, ay0, az0, r1, oct);
        const float2 a1 = enc_dense<DS0, DOFF0>(ax1, ay1, az1, r0, oct);
        const float2 b1 = enc_dense<DS1, DOFF1>(ax1, ay1, az1, r1, oct);
        d0[0] = make_float4(a0.x, a0.y, b0.x, b0.y);
        d1[0] = make_float4(a1.x, a1.y, b1.x, b1.y);
        __syncthreads();
    }
    {
        const float r2 = resolution[2], r3 = resolution[3];
        const float2 a0 = enc_dense<DS2, DOFF2>(ax0, ay0, az0, r2, oct);
        const float2 b0 = enc_dense<DS3, DOFF3>(ax0, ay0, az0, r3, oct);
        const float2 a1 = enc_dense<DS2, DOFF2>(ax1, ay1, az1, r2, oct);
        const float2 b1 = enc_dense<DS3, DOFF3>(ax1, ay1, az1, r3, oct);
        d0[1] = make_float4(a0.x, a0.y, b0.x, b0.y);
        d1[1] = make_float4(a1.x, a1.y, b1.x, b1.y);
        __syncthreads();
    }
    // ---- dense levels 4..5 last (23.5MB, streams; drift-tolerant) ----
    {
        const float r4 = resolution[4], r5 = resolution[5];
        const float2 a0 = enc_dense<DS4, DOFF4>(ax0, ay0, az0, r4, oct);
        const float2 b0 = enc_dense<DS5, DOFF5>(ax0, ay0, az0, r5, oct);
        const float2 a1 = enc_dense<DS4, DOFF4>(ax1, ay1, az1, r4, oct);
        const float2 b1 = enc_dense<DS5, DOFF5>(ax1, ay1, az1, r5, oct);
        d0[2] = make_float4(a0.x, a0.y, b0.x, b0.y);
        d1[2] = make_float4(a1.x, a1.y, b1.x, b1.y);
    }
}

extern "C" void kernel_launch(void* const* d_in, const int* in_sizes, int n_in,
                              void* d_out, int out_size, void* d_ws, size_t ws_size,
                              hipStream_t stream) {
    const float* x          = (const float*)d_in[0];
    const float* hashmap    = (const float*)d_in[1];
    const float* resolution = (const float*)d_in[2];
    float* out              = (float*)d_out;

    __half2* wst = (__half2*)d_ws;                         // 20.97 MB hashed tables
    uint4*   oct = (uint4*)((char*)d_ws + TAB_BYTES);      // 27.6 MB oct lattices
    const uint2* tab2 = (const uint2*)d_ws;

    hipLaunchKernelGGL(hg_prep, dim3(NB_INTER + NB_OCT), dim3(256), 0, stream,
                       hashmap, wst, oct);

    hipLaunchKernelGGL(hg_main, dim3(HG_N / 512u), dim3(256), 0, stream,
                       x, tab2, oct, resolution, out);
}